// Round 1
// baseline (142.828 us; speedup 1.0000x reference)
//
#include <hip/hip_runtime.h>

typedef __attribute__((ext_vector_type(8))) short s16x8;
typedef __attribute__((ext_vector_type(4))) float f32x4;

union FragU {
    unsigned int u[4];
    uint4 v;
    s16x8 s;
};

// ---------------------------------------------------------------------------
// Workspace layout (bytes):
//   [0..12)      : s1, s2, so  (f32 scales, power of two)
//   [16..272)    : Woutq as f32 (int-valued, 64 entries)
//   [512..33280) : W1 frag-ordered bf16  [ks(8)][c(4)][lane(64)][j(8)]
//   [33280..41472): W2 frag-ordered bf16 [ks(2)][c(4)][lane(64)][j(8)]
// ---------------------------------------------------------------------------

__device__ __forceinline__ void pow2_scale(float ma, float& scale, float& inv) {
    ma = fmaxf(ma, 1e-12f);
    unsigned u = __float_as_uint(ma);
    int E = (int)((u >> 23) & 255u);
    unsigned fr = u & 0x7fffffu;
    int ce = (fr == 0u) ? (E - 127) : (E - 126);   // ceil(log2(ma)) exactly
    int se = ce - 7;                               // scale = 2^ce / 128
    scale = __uint_as_float((unsigned)(se + 127) << 23);
    inv   = __uint_as_float((unsigned)(127 - se) << 23);
}

__global__ void prep_kernel(const float* __restrict__ W1,
                            const float* __restrict__ W2,
                            const float* __restrict__ Wo,
                            float* __restrict__ wsf) {
    __shared__ float red[256];
    const int t = threadIdx.x;

    // max|W1|
    float m = 0.f;
    for (int i = t; i < 64 * 256; i += 256) m = fmaxf(m, fabsf(W1[i]));
    red[t] = m; __syncthreads();
    for (int s = 128; s > 0; s >>= 1) { if (t < s) red[t] = fmaxf(red[t], red[t + s]); __syncthreads(); }
    const float ma1 = red[0]; __syncthreads();

    // max|W2|
    m = 0.f;
    for (int i = t; i < 64 * 64; i += 256) m = fmaxf(m, fabsf(W2[i]));
    red[t] = m; __syncthreads();
    for (int s = 128; s > 0; s >>= 1) { if (t < s) red[t] = fmaxf(red[t], red[t + s]); __syncthreads(); }
    const float ma2 = red[0]; __syncthreads();

    // max|Wout|
    m = 0.f;
    for (int i = t; i < 64; i += 256) m = fmaxf(m, fabsf(Wo[i]));
    red[t] = m; __syncthreads();
    for (int s = 128; s > 0; s >>= 1) { if (t < s) red[t] = fmaxf(red[t], red[t + s]); __syncthreads(); }
    const float mao = red[0];

    float s1, i1, s2, i2, so, io;
    pow2_scale(ma1, s1, i1);
    pow2_scale(ma2, s2, i2);
    pow2_scale(mao, so, io);
    if (t == 0) { wsf[0] = s1; wsf[1] = s2; wsf[2] = so; }

    // Wout quantized (store as f32 int-values)
    float* woq = wsf + 4;
    for (int i = t; i < 64; i += 256) {
        float q = rintf(Wo[i] * io);
        q = fminf(fmaxf(q, -128.f), 127.f);
        woq[i] = q;
    }

    // W1 -> frag-ordered bf16 (exact: int8 values)
    unsigned short* w1dst = (unsigned short*)((char*)wsf + 512);
    for (int i = t; i < 64 * 256; i += 256) {
        int u = i >> 8, k = i & 255;
        float q = rintf(W1[i] * i1);
        q = fminf(fmaxf(q, -128.f), 127.f);
        int c = u >> 4, cc = u & 15, s = k >> 5, g = (k >> 3) & 3, j = k & 7;
        int pos = ((s * 4 + c) * 64 + g * 16 + cc) * 8 + j;
        w1dst[pos] = (unsigned short)(__float_as_uint(q) >> 16);  // exact bf16
    }

    // W2 -> frag-ordered bf16
    unsigned short* w2dst = (unsigned short*)((char*)wsf + 512 + 32768);
    for (int i = t; i < 64 * 64; i += 256) {
        int v = i >> 6, k = i & 63;
        float q = rintf(W2[i] * i2);
        q = fminf(fmaxf(q, -128.f), 127.f);
        int c = v >> 4, cc = v & 15, s = k >> 5, g = (k >> 3) & 3, j = k & 7;
        int pos = ((s * 4 + c) * 64 + g * 16 + cc) * 8 + j;
        w2dst[pos] = (unsigned short)(__float_as_uint(q) >> 16);
    }
}

__global__ __launch_bounds__(256) void fused_kernel(
    const float* __restrict__ x,
    const float* __restrict__ b1,
    const float* __restrict__ b2,
    const float* __restrict__ boutp,
    const float* __restrict__ a1p,
    const float* __restrict__ a2p,
    const float* __restrict__ wsf,
    float* __restrict__ out,
    int ntiles, int nwaves) {

    __shared__ __align__(16) unsigned short w1f[16384];
    __shared__ __align__(16) unsigned short w2f[4096];
    __shared__ __align__(16) unsigned short stg[4][1024];

    const int t = threadIdx.x;

    // stage weights to LDS (frag layout, lane-linear)
    {
        const uint4* sp1 = (const uint4*)((const char*)wsf + 512);
        uint4* d1 = (uint4*)w1f;
        #pragma unroll
        for (int i = 0; i < 8; ++i) d1[t + 256 * i] = sp1[t + 256 * i];
        const uint4* sp2 = (const uint4*)((const char*)wsf + 512 + 32768);
        uint4* d2 = (uint4*)w2f;
        #pragma unroll
        for (int i = 0; i < 2; ++i) d2[t + 256 * i] = sp2[t + 256 * i];
    }
    __syncthreads();

    const float s1 = wsf[0], s2 = wsf[1], so = wsf[2];
    const float a1 = a1p[0], a2 = a2p[0];
    const float boutv = boutp[0];
    const float c21 = a1 * s2;   // exact: s2 is a power of two
    const float c3  = a2 * so;   // exact: so is a power of two

    const int lane = t & 63;
    const int wv = t >> 6;
    const int cc = lane & 15;    // row-within-tile selector (A) / col selector (B,D)
    const int g  = lane >> 4;    // k-group / D row-group

    float b1c[4], b2c[4], wqc[4];
    #pragma unroll
    for (int c = 0; c < 4; ++c) {
        b1c[c] = b1[c * 16 + cc];
        b2c[c] = b2[c * 16 + cc];
        wqc[c] = wsf[4 + c * 16 + cc];
    }

    unsigned short* st = stg[wv];
    const int gw0 = blockIdx.x * 4 + wv;

    for (int tile = gw0; tile < ntiles; tile += nwaves) {
        const float* xp = x + (size_t)(tile * 16 + cc) * 256 + g * 8;

        // preload the whole 16x256 f32 slab fragment for this lane (16 dwordx4 in flight)
        float4 xv[16];
        #pragma unroll
        for (int ks = 0; ks < 8; ++ks) {
            xv[2 * ks]     = *(const float4*)(xp + ks * 32);
            xv[2 * ks + 1] = *(const float4*)(xp + ks * 32 + 4);
        }

        f32x4 acc[4];
        #pragma unroll
        for (int c = 0; c < 4; ++c) acc[c] = (f32x4){0.f, 0.f, 0.f, 0.f};

        #pragma unroll
        for (int ks = 0; ks < 8; ++ks) {
            float xf[8] = {xv[2*ks].x, xv[2*ks].y, xv[2*ks].z, xv[2*ks].w,
                           xv[2*ks+1].x, xv[2*ks+1].y, xv[2*ks+1].z, xv[2*ks+1].w};
            // exact 3-way bf16 split: x = hi + lo + lo2 (truncation captures 8+8+8 bits)
            FragU hi, lo, lo2;
            #pragma unroll
            for (int p = 0; p < 4; ++p) {
                float f0 = xf[2*p], f1 = xf[2*p+1];
                unsigned u0 = __float_as_uint(f0), u1 = __float_as_uint(f1);
                unsigned h0 = u0 & 0xffff0000u, h1 = u1 & 0xffff0000u;
                hi.u[p] = (u0 >> 16) | h1;
                float r0 = f0 - __uint_as_float(h0);
                float r1 = f1 - __uint_as_float(h1);
                unsigned v0 = __float_as_uint(r0), v1 = __float_as_uint(r1);
                unsigned m0 = v0 & 0xffff0000u, m1 = v1 & 0xffff0000u;
                lo.u[p] = (v0 >> 16) | m1;
                float q0 = r0 - __uint_as_float(m0);
                float q1 = r1 - __uint_as_float(m1);
                lo2.u[p] = (__float_as_uint(q0) >> 16) | (__float_as_uint(q1) & 0xffff0000u);
            }
            #pragma unroll
            for (int c = 0; c < 4; ++c) {
                FragU b;
                b.v = *(const uint4*)&w1f[((ks * 4 + c) * 64 + lane) * 8];
                acc[c] = __builtin_amdgcn_mfma_f32_16x16x32_bf16(hi.s,  b.s, acc[c], 0, 0, 0);
                acc[c] = __builtin_amdgcn_mfma_f32_16x16x32_bf16(lo.s,  b.s, acc[c], 0, 0, 0);
                acc[c] = __builtin_amdgcn_mfma_f32_16x16x32_bf16(lo2.s, b.s, acc[c], 0, 0, 0);
            }
        }

        // ---- layer-1 epilogue: h1 = acc*s1 + b1 ; quant-relu -> int 0..255 ; stage
        //      into A-frag layout for layer 2 (wave-private LDS region)
        #pragma unroll
        for (int c = 0; c < 4; ++c) {
            #pragma unroll
            for (int j = 0; j < 4; ++j) {
                float h = fmaf(acc[c][j], s1, b1c[c]);  // acc*s1 exact (pow2)
                h = fmaxf(h, 0.f);
                float n = rintf(h / a1);
                n = fminf(n, 255.f);
                int r = g * 4 + j;
                int u = c * 16 + cc;
                int pos = ((u >> 5) * 64 + ((u >> 3) & 3) * 16 + r) * 8 + (u & 7);
                st[pos] = (unsigned short)(__float_as_uint(n) >> 16);  // exact bf16 int
            }
        }
        asm volatile("s_waitcnt lgkmcnt(0)" ::: "memory");  // wave-private: no barrier needed

        s16x8 afrag[2];
        #pragma unroll
        for (int s = 0; s < 2; ++s) {
            FragU a;
            a.v = *(const uint4*)&st[(s * 64 + lane) * 8];
            afrag[s] = a.s;
        }

        f32x4 acc2[4];
        #pragma unroll
        for (int c = 0; c < 4; ++c) acc2[c] = (f32x4){0.f, 0.f, 0.f, 0.f};
        #pragma unroll
        for (int s = 0; s < 2; ++s) {
            #pragma unroll
            for (int c = 0; c < 4; ++c) {
                FragU b;
                b.v = *(const uint4*)&w2f[((s * 4 + c) * 64 + lane) * 8];
                acc2[c] = __builtin_amdgcn_mfma_f32_16x16x32_bf16(afrag[s], b.s, acc2[c], 0, 0, 0);
            }
        }

        // ---- layer-2 epilogue + layer-3 dot (all integer-exact until final scaling)
        float psum[4] = {0.f, 0.f, 0.f, 0.f};
        #pragma unroll
        for (int c = 0; c < 4; ++c) {
            #pragma unroll
            for (int j = 0; j < 4; ++j) {
                float h = fmaf(acc2[c][j], c21, b2c[c]);  // (int-exact acc)*a1*s2 + b2
                h = fmaxf(h, 0.f);
                float n = rintf(h / a2);
                n = fminf(n, 255.f);
                psum[j] = fmaf(n, wqc[c], psum[j]);       // exact int accumulation
            }
        }
        #pragma unroll
        for (int j = 0; j < 4; ++j) {
            #pragma unroll
            for (int mask = 1; mask < 16; mask <<= 1)
                psum[j] += __shfl_xor(psum[j], mask, 16); // exact int adds
        }

        if (cc == 0) {
            float4 o;
            o.x = fmaf(psum[0], c3, boutv);
            o.y = fmaf(psum[1], c3, boutv);
            o.z = fmaf(psum[2], c3, boutv);
            o.w = fmaf(psum[3], c3, boutv);
            *(float4*)(out + (size_t)tile * 16 + g * 4) = o;
        }
    }
}

extern "C" void kernel_launch(void* const* d_in, const int* in_sizes, int n_in,
                              void* d_out, int out_size, void* d_ws, size_t ws_size,
                              hipStream_t stream) {
    const float* x    = (const float*)d_in[0];
    const float* W1   = (const float*)d_in[1];
    const float* b1   = (const float*)d_in[2];
    const float* W2   = (const float*)d_in[3];
    const float* b2   = (const float*)d_in[4];
    const float* Wout = (const float*)d_in[5];
    const float* bout = (const float*)d_in[6];
    const float* a1   = (const float*)d_in[7];
    const float* a2   = (const float*)d_in[8];
    float* out = (float*)d_out;
    float* wsf = (float*)d_ws;

    const int rows = in_sizes[0] / 256;
    const int ntiles = rows / 16;            // 31250 for B=500000

    prep_kernel<<<1, 256, 0, stream>>>(W1, W2, Wout, wsf);

    int blocks = 768;
    if (blocks * 4 > ntiles) blocks = (ntiles + 3) / 4;
    const int nwaves = blocks * 4;
    fused_kernel<<<blocks, 256, 0, stream>>>(x, b1, b2, bout, a1, a2, wsf, out,
                                             ntiles, nwaves);
}

// Round 2
// 116.652 us; speedup vs baseline: 1.2244x; 1.2244x over previous
//
#include <hip/hip_runtime.h>

typedef __attribute__((ext_vector_type(8))) short s16x8;
typedef __attribute__((ext_vector_type(4))) float f32x4;

union FragU {
    unsigned int u[4];
    uint4 v;
    s16x8 s;
};

// scale = 2^ceil(log2(max(ma,1e-12)))/128 ; returns 1/scale. Both exact pow2.
__device__ __forceinline__ float pow2_scale_inv(float ma, float& scale) {
    ma = fmaxf(ma, 1e-12f);
    unsigned u = __float_as_uint(ma);
    int E = (int)((u >> 23) & 255u);
    int ce = ((u & 0x7fffffu) == 0u) ? (E - 127) : (E - 126);  // ceil(log2(ma))
    int se = ce - 7;                                            // scale = 2^ce/128
    scale = __uint_as_float((unsigned)(se + 127) << 23);
    return __uint_as_float((unsigned)(127 - se) << 23);
}

__global__ __launch_bounds__(256) void fused_kernel(
    const float* __restrict__ x,
    const float* __restrict__ W1,
    const float* __restrict__ b1,
    const float* __restrict__ W2,
    const float* __restrict__ b2,
    const float* __restrict__ Wo,
    const float* __restrict__ boutp,
    const float* __restrict__ a1p,
    const float* __restrict__ a2p,
    float* __restrict__ out,
    int ntiles, int nwaves) {

    __shared__ __align__(16) unsigned short w1f[16384];     // 32 KB: W1 frags
    __shared__ __align__(16) unsigned short w2f[4096];      //  8 KB: W2 frags
    __shared__ __align__(16) unsigned short stg[4][1024];   //  8 KB: per-wave h1q staging
    __shared__ float redm[12];

    const int t = threadIdx.x;
    const int lane = t & 63;
    const int wv = t >> 6;

    // ================= per-block weight prep (replicated, ~3 us parallel) =====
    // Load W slices into registers (coalesced float4), compute max-abs.
    float4 w1v[16];
    float4 w2v[4];
    float m1 = 0.f, m2 = 0.f, mo = 0.f;
    #pragma unroll
    for (int k = 0; k < 16; ++k) {
        w1v[k] = *(const float4*)(W1 + 4 * (t + 256 * k));
        m1 = fmaxf(m1, fmaxf(fmaxf(fabsf(w1v[k].x), fabsf(w1v[k].y)),
                             fmaxf(fabsf(w1v[k].z), fabsf(w1v[k].w))));
    }
    #pragma unroll
    for (int k = 0; k < 4; ++k) {
        w2v[k] = *(const float4*)(W2 + 4 * (t + 256 * k));
        m2 = fmaxf(m2, fmaxf(fmaxf(fabsf(w2v[k].x), fabsf(w2v[k].y)),
                             fmaxf(fabsf(w2v[k].z), fabsf(w2v[k].w))));
    }
    if (t < 64) mo = fabsf(Wo[t]);

    #pragma unroll
    for (int m = 1; m < 64; m <<= 1) {
        m1 = fmaxf(m1, __shfl_xor(m1, m, 64));
        m2 = fmaxf(m2, __shfl_xor(m2, m, 64));
        mo = fmaxf(mo, __shfl_xor(mo, m, 64));
    }
    if (lane == 0) { redm[wv] = m1; redm[4 + wv] = m2; redm[8 + wv] = mo; }
    __syncthreads();
    m1 = fmaxf(fmaxf(redm[0], redm[1]), fmaxf(redm[2], redm[3]));
    m2 = fmaxf(fmaxf(redm[4], redm[5]), fmaxf(redm[6], redm[7]));
    mo = fmaxf(fmaxf(redm[8], redm[9]), fmaxf(redm[10], redm[11]));

    float s1, s2, so;
    const float i1 = pow2_scale_inv(m1, s1);
    const float i2 = pow2_scale_inv(m2, s2);
    const float io = pow2_scale_inv(mo, so);

    // Quantize W1/W2 from registers into LDS frag layout (exact int8 -> bf16).
    #pragma unroll
    for (int k = 0; k < 16; ++k) {
        const int i0 = 4 * (t + 256 * k);
        float q4[4] = {w1v[k].x, w1v[k].y, w1v[k].z, w1v[k].w};
        #pragma unroll
        for (int e = 0; e < 4; ++e) {
            const int i = i0 + e;
            float q = fminf(fmaxf(rintf(q4[e] * i1), -128.f), 127.f);
            const int u = i >> 8, kk = i & 255;
            const int c = u >> 4, ccb = u & 15, s = kk >> 5, gg = (kk >> 3) & 3, j = kk & 7;
            w1f[((s * 4 + c) * 64 + gg * 16 + ccb) * 8 + j] =
                (unsigned short)(__float_as_uint(q) >> 16);
        }
    }
    #pragma unroll
    for (int k = 0; k < 4; ++k) {
        const int i0 = 4 * (t + 256 * k);
        float q4[4] = {w2v[k].x, w2v[k].y, w2v[k].z, w2v[k].w};
        #pragma unroll
        for (int e = 0; e < 4; ++e) {
            const int i = i0 + e;
            float q = fminf(fmaxf(rintf(q4[e] * i2), -128.f), 127.f);
            const int v = i >> 6, kk = i & 63;
            const int c = v >> 4, ccb = v & 15, s = kk >> 5, gg = (kk >> 3) & 3, j = kk & 7;
            w2f[((s * 4 + c) * 64 + gg * 16 + ccb) * 8 + j] =
                (unsigned short)(__float_as_uint(q) >> 16);
        }
    }
    __syncthreads();

    // ================= main streaming loop =====================================
    const float a1 = a1p[0], a2 = a2p[0];
    const float boutv = boutp[0];
    const float c21 = a1 * s2;   // exact: s2 pow2
    const float c3  = a2 * so;   // exact: so pow2

    const int cc = lane & 15;    // row-within-tile (A) / col (B,D)
    const int g  = lane >> 4;    // k-group / D row-group

    float b1c[4], b2c[4], wqc[4];
    #pragma unroll
    for (int c = 0; c < 4; ++c) {
        b1c[c] = b1[c * 16 + cc];
        b2c[c] = b2[c * 16 + cc];
        wqc[c] = fminf(fmaxf(rintf(Wo[c * 16 + cc] * io), -128.f), 127.f);
    }

    unsigned short* st = stg[wv];
    const int gw0 = blockIdx.x * 4 + wv;

    // Prologue: load first tile's slab fragment (16 dwordx4 per lane).
    float4 xv[16];
    if (gw0 < ntiles) {
        const float* xp = x + (size_t)(gw0 * 16 + cc) * 256 + g * 8;
        #pragma unroll
        for (int ks = 0; ks < 8; ++ks) {
            xv[2 * ks]     = *(const float4*)(xp + ks * 32);
            xv[2 * ks + 1] = *(const float4*)(xp + ks * 32 + 4);
        }
    }

    for (int tile = gw0; tile < ntiles; tile += nwaves) {
        const int nt = tile + nwaves;
        const bool pf = nt < ntiles;                     // wave-uniform
        const float* xpn = x + (size_t)(nt * 16 + cc) * 256 + g * 8;

        f32x4 acc[4];
        #pragma unroll
        for (int c = 0; c < 4; ++c) acc[c] = (f32x4){0.f, 0.f, 0.f, 0.f};

        #pragma unroll
        for (int ks = 0; ks < 8; ++ks) {
            float xf[8] = {xv[2*ks].x, xv[2*ks].y, xv[2*ks].z, xv[2*ks].w,
                           xv[2*ks+1].x, xv[2*ks+1].y, xv[2*ks+1].z, xv[2*ks+1].w};
            // exact 3-way bf16 split: x = hi + lo + lo2
            FragU hi, lo, lo2;
            #pragma unroll
            for (int p = 0; p < 4; ++p) {
                float f0 = xf[2*p], f1 = xf[2*p+1];
                unsigned u0 = __float_as_uint(f0), u1 = __float_as_uint(f1);
                unsigned h0 = u0 & 0xffff0000u, h1 = u1 & 0xffff0000u;
                hi.u[p] = (u0 >> 16) | h1;
                float r0 = f0 - __uint_as_float(h0);
                float r1 = f1 - __uint_as_float(h1);
                unsigned v0 = __float_as_uint(r0), v1 = __float_as_uint(r1);
                unsigned m0 = v0 & 0xffff0000u, m1_ = v1 & 0xffff0000u;
                lo.u[p] = (v0 >> 16) | m1_;
                float q0 = r0 - __uint_as_float(m0);
                float q1 = r1 - __uint_as_float(m1_);
                lo2.u[p] = (__float_as_uint(q0) >> 16) | (__float_as_uint(q1) & 0xffff0000u);
            }
            // rotating prefetch: xv[2ks..2ks+1] dead now -> refill from next tile
            if (pf) {
                xv[2 * ks]     = *(const float4*)(xpn + ks * 32);
                xv[2 * ks + 1] = *(const float4*)(xpn + ks * 32 + 4);
            }
            #pragma unroll
            for (int c = 0; c < 4; ++c) {
                FragU b;
                b.v = *(const uint4*)&w1f[((ks * 4 + c) * 64 + lane) * 8];
                acc[c] = __builtin_amdgcn_mfma_f32_16x16x32_bf16(hi.s,  b.s, acc[c], 0, 0, 0);
                acc[c] = __builtin_amdgcn_mfma_f32_16x16x32_bf16(lo.s,  b.s, acc[c], 0, 0, 0);
                acc[c] = __builtin_amdgcn_mfma_f32_16x16x32_bf16(lo2.s, b.s, acc[c], 0, 0, 0);
            }
        }

        // ---- layer-1 epilogue: quant-relu -> A-frag staging (wave-private) ----
        #pragma unroll
        for (int c = 0; c < 4; ++c) {
            #pragma unroll
            for (int j = 0; j < 4; ++j) {
                float h = fmaf(acc[c][j], s1, b1c[c]);   // acc*s1 exact (pow2)
                h = fmaxf(h, 0.f);
                float n = rintf(h / a1);
                n = fminf(n, 255.f);
                const int r = g * 4 + j;
                const int u = c * 16 + cc;
                const int pos = ((u >> 5) * 64 + ((u >> 3) & 3) * 16 + r) * 8 + (u & 7);
                st[pos] = (unsigned short)(__float_as_uint(n) >> 16);  // exact bf16 int
            }
        }
        asm volatile("s_waitcnt lgkmcnt(0)" ::: "memory");  // wave-private: no barrier

        s16x8 afrag[2];
        #pragma unroll
        for (int s = 0; s < 2; ++s) {
            FragU a;
            a.v = *(const uint4*)&st[(s * 64 + lane) * 8];
            afrag[s] = a.s;
        }

        f32x4 acc2[4];
        #pragma unroll
        for (int c = 0; c < 4; ++c) acc2[c] = (f32x4){0.f, 0.f, 0.f, 0.f};
        #pragma unroll
        for (int s = 0; s < 2; ++s) {
            #pragma unroll
            for (int c = 0; c < 4; ++c) {
                FragU b;
                b.v = *(const uint4*)&w2f[((s * 4 + c) * 64 + lane) * 8];
                acc2[c] = __builtin_amdgcn_mfma_f32_16x16x32_bf16(afrag[s], b.s, acc2[c], 0, 0, 0);
            }
        }

        // ---- layer-2 epilogue + layer-3 dot (integer-exact until final scale) ----
        float psum[4] = {0.f, 0.f, 0.f, 0.f};
        #pragma unroll
        for (int c = 0; c < 4; ++c) {
            #pragma unroll
            for (int j = 0; j < 4; ++j) {
                float h = fmaf(acc2[c][j], c21, b2c[c]);
                h = fmaxf(h, 0.f);
                float n = rintf(h / a2);
                n = fminf(n, 255.f);
                psum[j] = fmaf(n, wqc[c], psum[j]);      // exact int accumulation
            }
        }
        #pragma unroll
        for (int j = 0; j < 4; ++j) {
            #pragma unroll
            for (int mask = 1; mask < 16; mask <<= 1)
                psum[j] += __shfl_xor(psum[j], mask, 16);
        }

        if (cc == 0) {
            float4 o;
            o.x = fmaf(psum[0], c3, boutv);
            o.y = fmaf(psum[1], c3, boutv);
            o.z = fmaf(psum[2], c3, boutv);
            o.w = fmaf(psum[3], c3, boutv);
            *(float4*)(out + (size_t)tile * 16 + g * 4) = o;
        }
    }
}

extern "C" void kernel_launch(void* const* d_in, const int* in_sizes, int n_in,
                              void* d_out, int out_size, void* d_ws, size_t ws_size,
                              hipStream_t stream) {
    const float* x    = (const float*)d_in[0];
    const float* W1   = (const float*)d_in[1];
    const float* b1   = (const float*)d_in[2];
    const float* W2   = (const float*)d_in[3];
    const float* b2   = (const float*)d_in[4];
    const float* Wout = (const float*)d_in[5];
    const float* bout = (const float*)d_in[6];
    const float* a1   = (const float*)d_in[7];
    const float* a2   = (const float*)d_in[8];
    float* out = (float*)d_out;

    const int rows = in_sizes[0] / 256;
    const int ntiles = rows / 16;            // 31250 for B=500000

    int blocks = 768;
    if (blocks * 4 > ntiles) blocks = (ntiles + 3) / 4;
    const int nwaves = blocks * 4;

    fused_kernel<<<blocks, 256, 0, stream>>>(x, W1, b1, W2, b2, Wout, bout,
                                             a1, a2, out, ntiles, nwaves);
}

// Round 3
// 106.517 us; speedup vs baseline: 1.3409x; 1.0951x over previous
//
#include <hip/hip_runtime.h>

typedef __attribute__((ext_vector_type(8))) short s16x8;
typedef __attribute__((ext_vector_type(4))) float f32x4;

union FragU {
    unsigned int u[4];
    uint4 v;
    s16x8 s;
};

// scale = 2^ceil(log2(max(ma,1e-12)))/128 ; returns 1/scale. Both exact pow2.
__device__ __forceinline__ float pow2_scale_inv(float ma, float& scale) {
    ma = fmaxf(ma, 1e-12f);
    unsigned u = __float_as_uint(ma);
    int E = (int)((u >> 23) & 255u);
    int ce = ((u & 0x7fffffu) == 0u) ? (E - 127) : (E - 126);  // ceil(log2(ma))
    int se = ce - 7;                                            // scale = 2^ce/128
    scale = __uint_as_float((unsigned)(se + 127) << 23);
    return __uint_as_float((unsigned)(127 - se) << 23);
}

// pack hi16 of two f32 bit patterns into one dword: [u1.hi16 : u0.hi16]
__device__ __forceinline__ unsigned pack_hi16(unsigned u0, unsigned u1) {
    return __builtin_amdgcn_perm(u1, u0, 0x07060302u);
}

__global__ __launch_bounds__(256, 3) void fused_kernel(
    const float* __restrict__ x,
    const float* __restrict__ W1,
    const float* __restrict__ b1,
    const float* __restrict__ W2,
    const float* __restrict__ b2,
    const float* __restrict__ Wo,
    const float* __restrict__ boutp,
    const float* __restrict__ a1p,
    const float* __restrict__ a2p,
    float* __restrict__ out,
    int ntiles, int nwaves) {

    __shared__ __align__(16) unsigned short w1f[16384];     // 32 KB: W1 frags
    __shared__ __align__(16) unsigned short w2f[4096];      //  8 KB: W2 frags
    __shared__ __align__(16) unsigned short stg[4][1024];   //  8 KB: per-wave h1q staging
    __shared__ float redm[12];

    const int t = threadIdx.x;
    const int lane = t & 63;
    const int wv = t >> 6;

    // ============ weight prep, pass 1: max-abs scan (no retention) ============
    float m1 = 0.f, m2 = 0.f, mo = 0.f;
    #pragma unroll 4
    for (int k = 0; k < 16; ++k) {
        float4 v = *(const float4*)(W1 + 4 * (t + 256 * k));
        m1 = fmaxf(m1, fmaxf(fmaxf(fabsf(v.x), fabsf(v.y)),
                             fmaxf(fabsf(v.z), fabsf(v.w))));
    }
    #pragma unroll
    for (int k = 0; k < 4; ++k) {
        float4 v = *(const float4*)(W2 + 4 * (t + 256 * k));
        m2 = fmaxf(m2, fmaxf(fmaxf(fabsf(v.x), fabsf(v.y)),
                             fmaxf(fabsf(v.z), fabsf(v.w))));
    }
    if (t < 64) mo = fabsf(Wo[t]);

    #pragma unroll
    for (int m = 1; m < 64; m <<= 1) {
        m1 = fmaxf(m1, __shfl_xor(m1, m, 64));
        m2 = fmaxf(m2, __shfl_xor(m2, m, 64));
        mo = fmaxf(mo, __shfl_xor(mo, m, 64));
    }
    if (lane == 0) { redm[wv] = m1; redm[4 + wv] = m2; redm[8 + wv] = mo; }
    __syncthreads();
    m1 = fmaxf(fmaxf(redm[0], redm[1]), fmaxf(redm[2], redm[3]));
    m2 = fmaxf(fmaxf(redm[4], redm[5]), fmaxf(redm[6], redm[7]));
    mo = fmaxf(fmaxf(redm[8], redm[9]), fmaxf(redm[10], redm[11]));

    float s1, s2, so;
    const float i1 = pow2_scale_inv(m1, s1);   // exact pow2: w*i1 == w/s1 bit-exact
    const float i2 = pow2_scale_inv(m2, s2);
    const float io = pow2_scale_inv(mo, so);

    const float a1 = a1p[0], a2 = a2p[0];
    // double-float reciprocals of a1, a2 (once per block; quotient err <= ~1 ulp)
    const double d1 = 1.0 / (double)a1;
    const float i1h = (float)d1, i1l = (float)(d1 - (double)i1h);
    const double d2 = 1.0 / (double)a2;
    const float i2h = (float)d2, i2l = (float)(d2 - (double)i2h);

    // ============ weight prep, pass 2: reload (L2-hit) + quantize to LDS ======
    #pragma unroll 4
    for (int k = 0; k < 16; ++k) {
        const int i0 = 4 * (t + 256 * k);
        float4 v = *(const float4*)(W1 + i0);
        float q4[4] = {v.x, v.y, v.z, v.w};
        #pragma unroll
        for (int e = 0; e < 4; ++e) {
            const int i = i0 + e;
            float q = fminf(fmaxf(rintf(q4[e] * i1), -128.f), 127.f);
            const int u = i >> 8, kk = i & 255;
            const int c = u >> 4, ccb = u & 15, s = kk >> 5, gg = (kk >> 3) & 3, j = kk & 7;
            w1f[((s * 4 + c) * 64 + gg * 16 + ccb) * 8 + j] =
                (unsigned short)(__float_as_uint(q) >> 16);   // exact bf16 int
        }
    }
    #pragma unroll
    for (int k = 0; k < 4; ++k) {
        const int i0 = 4 * (t + 256 * k);
        float4 v = *(const float4*)(W2 + i0);
        float q4[4] = {v.x, v.y, v.z, v.w};
        #pragma unroll
        for (int e = 0; e < 4; ++e) {
            const int i = i0 + e;
            float q = fminf(fmaxf(rintf(q4[e] * i2), -128.f), 127.f);
            const int vv = i >> 6, kk = i & 63;
            const int c = vv >> 4, ccb = vv & 15, s = kk >> 5, gg = (kk >> 3) & 3, j = kk & 7;
            w2f[((s * 4 + c) * 64 + gg * 16 + ccb) * 8 + j] =
                (unsigned short)(__float_as_uint(q) >> 16);
        }
    }
    __syncthreads();

    // ============ main streaming loop =========================================
    const float boutv = boutp[0];
    const float c21 = a1 * s2;   // exact: s2 pow2
    const float c3  = a2 * so;   // exact: so pow2

    const int cc = lane & 15;    // row-within-tile (A) / col (B,D)
    const int g  = lane >> 4;    // k-group / D row-group

    float b1c[4], b2c[4], wqc[4];
    #pragma unroll
    for (int c = 0; c < 4; ++c) {
        b1c[c] = b1[c * 16 + cc];
        b2c[c] = b2[c * 16 + cc];
        wqc[c] = fminf(fmaxf(rintf(Wo[c * 16 + cc] * io), -128.f), 127.f);
    }

    unsigned short* st = stg[wv];
    const int gw0 = blockIdx.x * 4 + wv;

    // software pipeline: 8 float4 slots = 4 k-steps ahead
    float4 xv[8];
    if (gw0 < ntiles) {
        const float* xp0 = x + (size_t)(gw0 * 16 + cc) * 256 + g * 8;
        #pragma unroll
        for (int s = 0; s < 4; ++s) {
            xv[2 * s]     = *(const float4*)(xp0 + s * 32);
            xv[2 * s + 1] = *(const float4*)(xp0 + s * 32 + 4);
        }
    }

    for (int tile = gw0; tile < ntiles; tile += nwaves) {
        const float* xp = x + (size_t)(tile * 16 + cc) * 256 + g * 8;
        const int nt = tile + nwaves;
        const bool pf = nt < ntiles;                         // wave-uniform
        const float* xpn = pf ? (x + (size_t)(nt * 16 + cc) * 256 + g * 8) : xp;

        f32x4 acc[4];
        #pragma unroll
        for (int c = 0; c < 4; ++c) acc[c] = (f32x4){0.f, 0.f, 0.f, 0.f};

        #pragma unroll
        for (int ks = 0; ks < 8; ++ks) {
            const int sl = ks & 3;
            const float4 A = xv[2 * sl];
            const float4 B = xv[2 * sl + 1];

            // refill slot with data 4 k-steps ahead (crosses into next tile)
            const float* pb = (ks < 4) ? (xp + (ks + 4) * 32) : (xpn + (ks - 4) * 32);
            xv[2 * sl]     = *(const float4*)(pb);
            xv[2 * sl + 1] = *(const float4*)(pb + 4);

            // exact 3-way bf16 split: x = hi + lo + lo2 (v_perm packing)
            float f[8] = {A.x, A.y, A.z, A.w, B.x, B.y, B.z, B.w};
            FragU hi, lo, lo2;
            #pragma unroll
            for (int p = 0; p < 4; ++p) {
                const float f0 = f[2 * p], f1 = f[2 * p + 1];
                const unsigned u0 = __float_as_uint(f0), u1 = __float_as_uint(f1);
                hi.u[p] = pack_hi16(u0, u1);
                const float r0 = f0 - __uint_as_float(u0 & 0xffff0000u);
                const float r1 = f1 - __uint_as_float(u1 & 0xffff0000u);
                const unsigned v0 = __float_as_uint(r0), v1 = __float_as_uint(r1);
                lo.u[p] = pack_hi16(v0, v1);
                const float q0 = r0 - __uint_as_float(v0 & 0xffff0000u);
                const float q1 = r1 - __uint_as_float(v1 & 0xffff0000u);
                lo2.u[p] = pack_hi16(__float_as_uint(q0), __float_as_uint(q1));
            }
            #pragma unroll
            for (int c = 0; c < 4; ++c) {
                FragU b;
                b.v = *(const uint4*)&w1f[((ks * 4 + c) * 64 + lane) * 8];
                acc[c] = __builtin_amdgcn_mfma_f32_16x16x32_bf16(hi.s,  b.s, acc[c], 0, 0, 0);
                acc[c] = __builtin_amdgcn_mfma_f32_16x16x32_bf16(lo.s,  b.s, acc[c], 0, 0, 0);
                acc[c] = __builtin_amdgcn_mfma_f32_16x16x32_bf16(lo2.s, b.s, acc[c], 0, 0, 0);
            }
        }

        // ---- layer-1 epilogue: quant-relu -> A-frag staging (wave-private) ----
        #pragma unroll
        for (int c = 0; c < 4; ++c) {
            #pragma unroll
            for (int j = 0; j < 4; ++j) {
                float h = fmaf(acc[c][j], s1, b1c[c]);   // acc*s1 exact (pow2)
                h = fmaxf(h, 0.f);
                float n = rintf(fmaf(h, i1l, h * i1h));  // DF-recip divide
                n = fminf(n, 255.f);
                const int r = g * 4 + j;
                const int u = c * 16 + cc;
                const int pos = ((u >> 5) * 64 + ((u >> 3) & 3) * 16 + r) * 8 + (u & 7);
                st[pos] = (unsigned short)(__float_as_uint(n) >> 16);  // exact bf16 int
            }
        }
        asm volatile("s_waitcnt lgkmcnt(0)" ::: "memory");  // wave-private: no barrier

        s16x8 afrag[2];
        #pragma unroll
        for (int s = 0; s < 2; ++s) {
            FragU a;
            a.v = *(const uint4*)&st[(s * 64 + lane) * 8];
            afrag[s] = a.s;
        }

        f32x4 acc2[4];
        #pragma unroll
        for (int c = 0; c < 4; ++c) acc2[c] = (f32x4){0.f, 0.f, 0.f, 0.f};
        #pragma unroll
        for (int s = 0; s < 2; ++s) {
            #pragma unroll
            for (int c = 0; c < 4; ++c) {
                FragU b;
                b.v = *(const uint4*)&w2f[((s * 4 + c) * 64 + lane) * 8];
                acc2[c] = __builtin_amdgcn_mfma_f32_16x16x32_bf16(afrag[s], b.s, acc2[c], 0, 0, 0);
            }
        }

        // ---- layer-2 epilogue + layer-3 dot (integer-exact accumulation) ----
        float psum[4] = {0.f, 0.f, 0.f, 0.f};
        #pragma unroll
        for (int c = 0; c < 4; ++c) {
            #pragma unroll
            for (int j = 0; j < 4; ++j) {
                float h = fmaf(acc2[c][j], c21, b2c[c]);
                h = fmaxf(h, 0.f);
                float n = rintf(fmaf(h, i2l, h * i2h));  // DF-recip divide
                n = fminf(n, 255.f);
                psum[j] = fmaf(n, wqc[c], psum[j]);      // exact int accumulation
            }
        }
        #pragma unroll
        for (int j = 0; j < 4; ++j) {
            #pragma unroll
            for (int mask = 1; mask < 16; mask <<= 1)
                psum[j] += __shfl_xor(psum[j], mask, 16);
        }

        if (cc == 0) {
            float4 o;
            o.x = fmaf(psum[0], c3, boutv);
            o.y = fmaf(psum[1], c3, boutv);
            o.z = fmaf(psum[2], c3, boutv);
            o.w = fmaf(psum[3], c3, boutv);
            *(float4*)(out + (size_t)tile * 16 + g * 4) = o;
        }
    }
}

extern "C" void kernel_launch(void* const* d_in, const int* in_sizes, int n_in,
                              void* d_out, int out_size, void* d_ws, size_t ws_size,
                              hipStream_t stream) {
    const float* x    = (const float*)d_in[0];
    const float* W1   = (const float*)d_in[1];
    const float* b1   = (const float*)d_in[2];
    const float* W2   = (const float*)d_in[3];
    const float* b2   = (const float*)d_in[4];
    const float* Wout = (const float*)d_in[5];
    const float* bout = (const float*)d_in[6];
    const float* a1   = (const float*)d_in[7];
    const float* a2   = (const float*)d_in[8];
    float* out = (float*)d_out;

    const int rows = in_sizes[0] / 256;
    const int ntiles = rows / 16;            // 31250 for B=500000

    int blocks = 768;                         // 3 blocks/CU resident
    if (blocks * 4 > ntiles) blocks = (ntiles + 3) / 4;
    const int nwaves = blocks * 4;

    fused_kernel<<<blocks, 256, 0, stream>>>(x, W1, b1, W2, b2, Wout, bout,
                                             a1, a2, out, ntiles, nwaves);
}

// Round 4
// 106.418 us; speedup vs baseline: 1.3421x; 1.0009x over previous
//
#include <hip/hip_runtime.h>

typedef __attribute__((ext_vector_type(8))) short s16x8;
typedef __attribute__((ext_vector_type(4))) float f32x4;

union FragU {
    unsigned int u[4];
    uint4 v;
    s16x8 s;
};

// scale = 2^ceil(log2(max(ma,1e-12)))/128 ; returns 1/scale. Both exact pow2.
__device__ __forceinline__ float pow2_scale_inv(float ma, float& scale) {
    ma = fmaxf(ma, 1e-12f);
    unsigned u = __float_as_uint(ma);
    int E = (int)((u >> 23) & 255u);
    int ce = ((u & 0x7fffffu) == 0u) ? (E - 127) : (E - 126);  // ceil(log2(ma))
    int se = ce - 7;                                            // scale = 2^ce/128
    scale = __uint_as_float((unsigned)(se + 127) << 23);
    return __uint_as_float((unsigned)(127 - se) << 23);
}

// pack hi16 of two f32 bit patterns into one dword: [u1.hi16 : u0.hi16]
__device__ __forceinline__ unsigned pack_hi16(unsigned u0, unsigned u1) {
    return __builtin_amdgcn_perm(u1, u0, 0x07060302u);
}

// force a block-uniform float into an SGPR (frees a VGPR, enables SALU use)
__device__ __forceinline__ float uni(float x) {
    return __uint_as_float((unsigned)__builtin_amdgcn_readfirstlane(__float_as_uint(x)));
}

__global__ __launch_bounds__(512, 4) void fused_kernel(
    const float* __restrict__ x,
    const float* __restrict__ W1,
    const float* __restrict__ b1,
    const float* __restrict__ W2,
    const float* __restrict__ b2,
    const float* __restrict__ Wo,
    const float* __restrict__ boutp,
    const float* __restrict__ a1p,
    const float* __restrict__ a2p,
    float* __restrict__ out,
    int ntiles, int nwaves) {

    // 56.1 KB total -> 2 blocks/CU (112 KB of 160), 8 waves share one weight image
    __shared__ __align__(16) unsigned short w1f[16384];     // 32 KB: W1 frags
    __shared__ __align__(16) unsigned short w2f[4096];      //  8 KB: W2 frags
    __shared__ __align__(16) unsigned short stg[8][1024];   // 16 KB: per-wave h1q staging
    __shared__ float redm[24];

    const int t = threadIdx.x;
    const int lane = t & 63;
    const int wv = t >> 6;

    // ============ weight prep, pass 1: max-abs scan (no retention) ============
    float m1 = 0.f, m2 = 0.f, mo = 0.f;
    #pragma unroll 4
    for (int k = 0; k < 8; ++k) {
        float4 v = *(const float4*)(W1 + 4 * (t + 512 * k));
        m1 = fmaxf(m1, fmaxf(fmaxf(fabsf(v.x), fabsf(v.y)),
                             fmaxf(fabsf(v.z), fabsf(v.w))));
    }
    #pragma unroll
    for (int k = 0; k < 2; ++k) {
        float4 v = *(const float4*)(W2 + 4 * (t + 512 * k));
        m2 = fmaxf(m2, fmaxf(fmaxf(fabsf(v.x), fabsf(v.y)),
                             fmaxf(fabsf(v.z), fabsf(v.w))));
    }
    if (t < 64) mo = fabsf(Wo[t]);

    #pragma unroll
    for (int m = 1; m < 64; m <<= 1) {
        m1 = fmaxf(m1, __shfl_xor(m1, m, 64));
        m2 = fmaxf(m2, __shfl_xor(m2, m, 64));
        mo = fmaxf(mo, __shfl_xor(mo, m, 64));
    }
    if (lane == 0) { redm[wv] = m1; redm[8 + wv] = m2; redm[16 + wv] = mo; }
    __syncthreads();
    m1 = fmaxf(fmaxf(fmaxf(redm[0], redm[1]), fmaxf(redm[2], redm[3])),
               fmaxf(fmaxf(redm[4], redm[5]), fmaxf(redm[6], redm[7])));
    m2 = fmaxf(fmaxf(fmaxf(redm[8], redm[9]), fmaxf(redm[10], redm[11])),
               fmaxf(fmaxf(redm[12], redm[13]), fmaxf(redm[14], redm[15])));
    mo = fmaxf(fmaxf(fmaxf(redm[16], redm[17]), fmaxf(redm[18], redm[19])),
               fmaxf(fmaxf(redm[20], redm[21]), fmaxf(redm[22], redm[23])));

    float s1v, s2v, sov;
    const float i1 = uni(pow2_scale_inv(m1, s1v));  // exact pow2
    const float i2 = uni(pow2_scale_inv(m2, s2v));
    const float io = uni(pow2_scale_inv(mo, sov));
    const float s1 = uni(s1v);

    const float a1 = uni(a1p[0]), a2 = uni(a2p[0]);
    // double-float reciprocals of a1, a2 (quotient err <= ~1 ulp)
    const double d1 = 1.0 / (double)a1;
    const float i1h = uni((float)d1), i1l = uni((float)(d1 - (double)(float)d1));
    const double d2 = 1.0 / (double)a2;
    const float i2h = uni((float)d2), i2l = uni((float)(d2 - (double)(float)d2));

    // ============ weight prep, pass 2: reload (L2-hit) + quantize to LDS ======
    #pragma unroll 4
    for (int k = 0; k < 8; ++k) {
        const int i0 = 4 * (t + 512 * k);
        float4 v = *(const float4*)(W1 + i0);
        float q4[4] = {v.x, v.y, v.z, v.w};
        #pragma unroll
        for (int e = 0; e < 4; ++e) {
            const int i = i0 + e;
            float q = fminf(fmaxf(rintf(q4[e] * i1), -128.f), 127.f);
            const int u = i >> 8, kk = i & 255;
            const int c = u >> 4, ccb = u & 15, s = kk >> 5, gg = (kk >> 3) & 3, j = kk & 7;
            w1f[((s * 4 + c) * 64 + gg * 16 + ccb) * 8 + j] =
                (unsigned short)(__float_as_uint(q) >> 16);   // exact bf16 int
        }
    }
    #pragma unroll
    for (int k = 0; k < 2; ++k) {
        const int i0 = 4 * (t + 512 * k);
        float4 v = *(const float4*)(W2 + i0);
        float q4[4] = {v.x, v.y, v.z, v.w};
        #pragma unroll
        for (int e = 0; e < 4; ++e) {
            const int i = i0 + e;
            float q = fminf(fmaxf(rintf(q4[e] * i2), -128.f), 127.f);
            const int vv = i >> 6, kk = i & 63;
            const int c = vv >> 4, ccb = vv & 15, s = kk >> 5, gg = (kk >> 3) & 3, j = kk & 7;
            w2f[((s * 4 + c) * 64 + gg * 16 + ccb) * 8 + j] =
                (unsigned short)(__float_as_uint(q) >> 16);
        }
    }
    __syncthreads();

    // ============ main streaming loop =========================================
    const float boutv = uni(boutp[0]);
    const float c21 = uni(a1 * s2v);   // exact: s2 pow2
    const float c3  = uni(a2 * sov);   // exact: so pow2

    const int cc = lane & 15;    // row-within-tile (A) / col (B,D)
    const int g  = lane >> 4;    // k-group / D row-group

    float b1c[4], b2c[4], wqc[4];
    #pragma unroll
    for (int c = 0; c < 4; ++c) {
        b1c[c] = b1[c * 16 + cc];
        b2c[c] = b2[c * 16 + cc];
        wqc[c] = fminf(fmaxf(rintf(Wo[c * 16 + cc] * io), -128.f), 127.f);
    }

    unsigned short* st = stg[wv];
    const int gw0 = blockIdx.x * 8 + wv;

    // software pipeline: 8 float4 slots = 4 k-steps ahead
    float4 xv[8];
    if (gw0 < ntiles) {
        const float* xp0 = x + (size_t)(gw0 * 16 + cc) * 256 + g * 8;
        #pragma unroll
        for (int s = 0; s < 4; ++s) {
            xv[2 * s]     = *(const float4*)(xp0 + s * 32);
            xv[2 * s + 1] = *(const float4*)(xp0 + s * 32 + 4);
        }
    }

    for (int tile = gw0; tile < ntiles; tile += nwaves) {
        const float* xp = x + (size_t)(tile * 16 + cc) * 256 + g * 8;
        const int nt = tile + nwaves;
        const bool pf = nt < ntiles;                         // wave-uniform
        const float* xpn = pf ? (x + (size_t)(nt * 16 + cc) * 256 + g * 8) : xp;

        f32x4 acc[4];
        #pragma unroll
        for (int c = 0; c < 4; ++c) acc[c] = (f32x4){0.f, 0.f, 0.f, 0.f};

        #pragma unroll
        for (int ks = 0; ks < 8; ++ks) {
            const int sl = ks & 3;
            const float4 A = xv[2 * sl];
            const float4 B = xv[2 * sl + 1];

            // refill slot with data 4 k-steps ahead (crosses into next tile)
            const float* pb = (ks < 4) ? (xp + (ks + 4) * 32) : (xpn + (ks - 4) * 32);
            xv[2 * sl]     = *(const float4*)(pb);
            xv[2 * sl + 1] = *(const float4*)(pb + 4);

            // exact 3-way bf16 split: x = hi + lo + lo2 (v_perm packing)
            float f[8] = {A.x, A.y, A.z, A.w, B.x, B.y, B.z, B.w};
            FragU hi, lo, lo2;
            #pragma unroll
            for (int p = 0; p < 4; ++p) {
                const float f0 = f[2 * p], f1 = f[2 * p + 1];
                const unsigned u0 = __float_as_uint(f0), u1 = __float_as_uint(f1);
                hi.u[p] = pack_hi16(u0, u1);
                const float r0 = f0 - __uint_as_float(u0 & 0xffff0000u);
                const float r1 = f1 - __uint_as_float(u1 & 0xffff0000u);
                const unsigned v0 = __float_as_uint(r0), v1 = __float_as_uint(r1);
                lo.u[p] = pack_hi16(v0, v1);
                const float q0 = r0 - __uint_as_float(v0 & 0xffff0000u);
                const float q1 = r1 - __uint_as_float(v1 & 0xffff0000u);
                lo2.u[p] = pack_hi16(__float_as_uint(q0), __float_as_uint(q1));
            }
            #pragma unroll
            for (int c = 0; c < 4; ++c) {
                FragU b;
                b.v = *(const uint4*)&w1f[((ks * 4 + c) * 64 + lane) * 8];
                acc[c] = __builtin_amdgcn_mfma_f32_16x16x32_bf16(hi.s,  b.s, acc[c], 0, 0, 0);
                acc[c] = __builtin_amdgcn_mfma_f32_16x16x32_bf16(lo.s,  b.s, acc[c], 0, 0, 0);
                acc[c] = __builtin_amdgcn_mfma_f32_16x16x32_bf16(lo2.s, b.s, acc[c], 0, 0, 0);
            }
        }

        // ---- layer-1 epilogue: quant-relu -> A-frag staging (wave-private) ----
        #pragma unroll
        for (int c = 0; c < 4; ++c) {
            #pragma unroll
            for (int j = 0; j < 4; ++j) {
                float h = fmaf(acc[c][j], s1, b1c[c]);   // acc*s1 exact (pow2)
                h = fmaxf(h, 0.f);
                float n = rintf(fmaf(h, i1l, h * i1h));  // DF-recip divide
                n = fminf(n, 255.f);
                const int r = g * 4 + j;
                const int u = c * 16 + cc;
                const int pos = ((u >> 5) * 64 + ((u >> 3) & 3) * 16 + r) * 8 + (u & 7);
                st[pos] = (unsigned short)(__float_as_uint(n) >> 16);  // exact bf16 int
            }
        }
        asm volatile("s_waitcnt lgkmcnt(0)" ::: "memory");  // wave-private: no barrier

        s16x8 afrag[2];
        #pragma unroll
        for (int s = 0; s < 2; ++s) {
            FragU a;
            a.v = *(const uint4*)&st[(s * 64 + lane) * 8];
            afrag[s] = a.s;
        }

        f32x4 acc2[4];
        #pragma unroll
        for (int c = 0; c < 4; ++c) acc2[c] = (f32x4){0.f, 0.f, 0.f, 0.f};
        #pragma unroll
        for (int s = 0; s < 2; ++s) {
            #pragma unroll
            for (int c = 0; c < 4; ++c) {
                FragU b;
                b.v = *(const uint4*)&w2f[((s * 4 + c) * 64 + lane) * 8];
                acc2[c] = __builtin_amdgcn_mfma_f32_16x16x32_bf16(afrag[s], b.s, acc2[c], 0, 0, 0);
            }
        }

        // ---- layer-2 epilogue + layer-3 dot (integer-exact accumulation) ----
        float psum[4] = {0.f, 0.f, 0.f, 0.f};
        #pragma unroll
        for (int c = 0; c < 4; ++c) {
            #pragma unroll
            for (int j = 0; j < 4; ++j) {
                float h = fmaf(acc2[c][j], c21, b2c[c]);
                h = fmaxf(h, 0.f);
                float n = rintf(fmaf(h, i2l, h * i2h));  // DF-recip divide
                n = fminf(n, 255.f);
                psum[j] = fmaf(n, wqc[c], psum[j]);      // exact int accumulation
            }
        }
        #pragma unroll
        for (int j = 0; j < 4; ++j) {
            #pragma unroll
            for (int mask = 1; mask < 16; mask <<= 1)
                psum[j] += __shfl_xor(psum[j], mask, 16);
        }

        if (cc == 0) {
            float4 o;
            o.x = fmaf(psum[0], c3, boutv);
            o.y = fmaf(psum[1], c3, boutv);
            o.z = fmaf(psum[2], c3, boutv);
            o.w = fmaf(psum[3], c3, boutv);
            *(float4*)(out + (size_t)tile * 16 + g * 4) = o;
        }
    }
}

extern "C" void kernel_launch(void* const* d_in, const int* in_sizes, int n_in,
                              void* d_out, int out_size, void* d_ws, size_t ws_size,
                              hipStream_t stream) {
    const float* x    = (const float*)d_in[0];
    const float* W1   = (const float*)d_in[1];
    const float* b1   = (const float*)d_in[2];
    const float* W2   = (const float*)d_in[3];
    const float* b2   = (const float*)d_in[4];
    const float* Wout = (const float*)d_in[5];
    const float* bout = (const float*)d_in[6];
    const float* a1   = (const float*)d_in[7];
    const float* a2   = (const float*)d_in[8];
    float* out = (float*)d_out;

    const int rows = in_sizes[0] / 256;
    const int ntiles = rows / 16;            // 31250 for B=500000

    int blocks = 512;                         // 2 blocks/CU, 4 waves/SIMD
    if (blocks * 8 > ntiles) blocks = (ntiles + 7) / 8;
    const int nwaves = blocks * 8;

    fused_kernel<<<blocks, 512, 0, stream>>>(x, W1, b1, W2, b2, Wout, bout,
                                             a1, a2, out, ntiles, nwaves);
}